// Round 1
// baseline (253.599 us; speedup 1.0000x reference)
//
#include <hip/hip_runtime.h>
#include <stdint.h>

typedef __attribute__((ext_vector_type(8))) short short8;
typedef __attribute__((ext_vector_type(8))) unsigned short u16x8;
typedef __attribute__((ext_vector_type(4))) float f32x4;

// round-to-nearest-even fp32 -> bf16 (finite inputs)
__device__ __forceinline__ uint16_t f2bf(float x) {
  uint32_t u = __float_as_uint(x);
  uint32_t r = (u + 0x7FFFu + ((u >> 16) & 1u)) >> 16;
  return (uint16_t)r;
}

// async global->LDS, 16B per lane. lds dest must be wave-uniform base (HW adds lane*16).
__device__ __forceinline__ void gl_lds16(const uint16_t* g, uint16_t* l) {
  __builtin_amdgcn_global_load_lds(
      (const __attribute__((address_space(1))) void*)g,
      (__attribute__((address_space(3))) void*)l, 16, 0, 0);
}

// ---------------- conversion kernels ----------------

__global__ __launch_bounds__(256) void cvt_f32_to_bf16(const float* __restrict__ in,
                                                       uint16_t* __restrict__ out) {
  long i = ((long)blockIdx.x * 256 + threadIdx.x) * 8;
  f32x4 v0 = *(const f32x4*)(in + i);
  f32x4 v1 = *(const f32x4*)(in + i + 4);
  u16x8 o;
  o[0] = f2bf(v0[0]); o[1] = f2bf(v0[1]); o[2] = f2bf(v0[2]); o[3] = f2bf(v0[3]);
  o[4] = f2bf(v1[0]); o[5] = f2bf(v1[1]); o[6] = f2bf(v1[2]); o[7] = f2bf(v1[3]);
  *(u16x8*)(out + i) = o;
}

// W [1024][1024] f32 -> WT [1024(n)][1024(k)] bf16 (3 matrices via blockIdx.z)
__global__ __launch_bounds__(64) void cvt_w_transpose(const float* __restrict__ W0,
                                                      const float* __restrict__ W1,
                                                      const float* __restrict__ W2,
                                                      uint16_t* __restrict__ WT) {
  const int z = blockIdx.z;
  const float* W = (z == 0) ? W0 : ((z == 1) ? W1 : W2);
  uint16_t* out = WT + (long)z * 1024 * 1024;
  const int n = blockIdx.x * 64 + threadIdx.x;  // column of W
  const int k0 = blockIdx.y * 128;
  for (int kk = 0; kk < 128; kk += 8) {
    u16x8 o;
#pragma unroll
    for (int j = 0; j < 8; j++) o[j] = f2bf(W[(long)(k0 + kk + j) * 1024 + n]);
    *(u16x8*)(out + (long)n * 1024 + k0 + kk) = o;
  }
}

// V [4*2048][1024] bf16 -> Vt [4][1024(d)][2048(s)] bf16
__global__ __launch_bounds__(256) void transpose_v(const uint16_t* __restrict__ V,
                                                   uint16_t* __restrict__ Vt) {
  __shared__ uint16_t tile[64][66];
  const int b = blockIdx.z;
  const int s0 = blockIdx.x * 64, d0 = blockIdx.y * 64;
  const int t = threadIdx.x;
  const int r = t >> 3, c = (t & 7) * 8;
  const uint16_t* Vb = V + (long)b * 2048 * 1024;
#pragma unroll
  for (int j = 0; j < 2; j++) {
    u16x8 v = *(const u16x8*)(Vb + (long)(s0 + r + 32 * j) * 1024 + d0 + c);
#pragma unroll
    for (int i = 0; i < 8; i++) tile[r + 32 * j][c + i] = v[i];
  }
  __syncthreads();
  uint16_t* Vtb = Vt + (long)b * 1024 * 2048;
#pragma unroll
  for (int j = 0; j < 2; j++) {
    const int d = r + 32 * j;
    u16x8 o;
#pragma unroll
    for (int i = 0; i < 8; i++) o[i] = tile[c + i][d];
    *(u16x8*)(Vtb + (long)(d0 + d) * 2048 + s0 + c) = o;
  }
}

// ---------------- softmax over rows of 2048 ----------------
__global__ __launch_bounds__(256) void softmax_rows(const float* __restrict__ Sc,
                                                    uint16_t* __restrict__ P) {
  const long row = blockIdx.x;
  const float* src = Sc + row * 2048;
  const int t = threadIdx.x;
  f32x4 v0 = *(const f32x4*)(src + t * 8);
  f32x4 v1 = *(const f32x4*)(src + t * 8 + 4);
  float m = fmaxf(fmaxf(fmaxf(v0[0], v0[1]), fmaxf(v0[2], v0[3])),
                  fmaxf(fmaxf(v1[0], v1[1]), fmaxf(v1[2], v1[3])));
#pragma unroll
  for (int off = 32; off >= 1; off >>= 1) m = fmaxf(m, __shfl_xor(m, off));
  __shared__ float redm[4];
  __shared__ float reds[4];
  if ((t & 63) == 0) redm[t >> 6] = m;
  __syncthreads();
  m = fmaxf(fmaxf(redm[0], redm[1]), fmaxf(redm[2], redm[3]));
  float e[8];
  e[0] = __expf(v0[0] - m); e[1] = __expf(v0[1] - m);
  e[2] = __expf(v0[2] - m); e[3] = __expf(v0[3] - m);
  e[4] = __expf(v1[0] - m); e[5] = __expf(v1[1] - m);
  e[6] = __expf(v1[2] - m); e[7] = __expf(v1[3] - m);
  float s = 0.f;
#pragma unroll
  for (int i = 0; i < 8; i++) s += e[i];
#pragma unroll
  for (int off = 32; off >= 1; off >>= 1) s += __shfl_xor(s, off);
  if ((t & 63) == 0) reds[t >> 6] = s;
  __syncthreads();
  s = reds[0] + reds[1] + reds[2] + reds[3];
  const float inv = 1.0f / s;
  u16x8 o;
#pragma unroll
  for (int i = 0; i < 8; i++) o[i] = f2bf(e[i] * inv);
  *(u16x8*)(P + row * 2048 + t * 8) = o;
}

// ---------------- NT GEMM: C[M,N] = A[M,K] * B[N,K]^T ----------------
// 128x128 tile, BK=32, 4 waves (each 64x64 = 4x4 frags of 16x16x32 bf16 MFMA).
// MODE 0: C = bf16(acc + bias[n])         (bias selected by blockIdx.z from e0/e1/e2)
// MODE 1: C = f32(acc*scale + mask[idx])
// MODE 2: C = f32(acc)
template <int MODE>
__global__ __launch_bounds__(256) void gemm_bt(
    const uint16_t* __restrict__ Abase, long sAz,  // byte strides per blockIdx.z
    const uint16_t* __restrict__ Bbase, long sBz,
    int K, int N,
    char* __restrict__ Cbase, long sCz,
    const float* __restrict__ e0, const float* __restrict__ e1,
    const float* __restrict__ e2,
    const float* __restrict__ maskb, long sMz, float scale) {
  __shared__ uint16_t Al[128 * 32];
  __shared__ uint16_t Bl[128 * 32];
  const int t = threadIdx.x;
  const int lane = t & 63;
  const int w = t >> 6;
  const int bm = blockIdx.x, bn = blockIdx.y, bz = blockIdx.z;

  const uint16_t* A = (const uint16_t*)((const char*)Abase + (long)bz * sAz);
  const uint16_t* Bm = (const uint16_t*)((const char*)Bbase + (long)bz * sBz);

  // staging: 256 threads x 16B = 4KB per shot; tile is 8KB -> 2 shots each
  const int sr = t >> 2;         // row 0..63 within shot
  const int sc = (t & 3) * 8;    // bf16 element offset within 32-elem row
  const uint16_t* ga0 = A + (long)(bm * 128 + sr) * K + sc;
  const uint16_t* ga1 = A + (long)(bm * 128 + 64 + sr) * K + sc;
  const uint16_t* gb0 = Bm + (long)(bn * 128 + sr) * K + sc;
  const uint16_t* gb1 = Bm + (long)(bn * 128 + 64 + sr) * K + sc;
  uint16_t* la0 = Al + w * 512;          // wave-uniform LDS bases
  uint16_t* la1 = Al + 2048 + w * 512;
  uint16_t* lb0 = Bl + w * 512;
  uint16_t* lb1 = Bl + 2048 + w * 512;

  f32x4 acc[4][4];
#pragma unroll
  for (int i = 0; i < 4; i++)
#pragma unroll
    for (int j = 0; j < 4; j++) acc[i][j] = (f32x4){0.f, 0.f, 0.f, 0.f};

  const int wm = w >> 1, wn = w & 1;
  const int fr = lane & 15, kg = lane >> 4;
  const uint16_t* afrag = Al + (wm * 64 + fr) * 32 + kg * 8;
  const uint16_t* bfrag = Bl + (wn * 64 + fr) * 32 + kg * 8;

  for (int k0 = 0; k0 < K; k0 += 32) {
    gl_lds16(ga0 + k0, la0);
    gl_lds16(ga1 + k0, la1);
    gl_lds16(gb0 + k0, lb0);
    gl_lds16(gb1 + k0, lb1);
    __syncthreads();  // drains vmcnt before barrier -> LDS tiles ready
    short8 a[4], b[4];
#pragma unroll
    for (int i = 0; i < 4; i++) a[i] = *(const short8*)(afrag + i * 16 * 32);
#pragma unroll
    for (int j = 0; j < 4; j++) b[j] = *(const short8*)(bfrag + j * 16 * 32);
#pragma unroll
    for (int i = 0; i < 4; i++)
#pragma unroll
      for (int j = 0; j < 4; j++)
        acc[i][j] = __builtin_amdgcn_mfma_f32_16x16x32_bf16(a[i], b[j], acc[i][j], 0, 0, 0);
    __syncthreads();  // protect LDS from next-iter staging
  }

  // epilogue: C/D frag layout col = lane&15, row = (lane>>4)*4 + reg  [m89]
  const int row0 = bm * 128 + wm * 64 + (kg << 2);
  const int col0 = bn * 128 + wn * 64 + fr;

  if (MODE == 0) {
    const float* bias = (bz == 0) ? e0 : ((bz == 1) ? e1 : e2);
    uint16_t* C = (uint16_t*)(Cbase + (long)bz * sCz);
#pragma unroll
    for (int i = 0; i < 4; i++) {
#pragma unroll
      for (int j = 0; j < 4; j++) {
        const float bv_ = bias[col0 + j * 16];
#pragma unroll
        for (int r = 0; r < 4; r++) {
          C[(long)(row0 + i * 16 + r) * N + col0 + j * 16] = f2bf(acc[i][j][r] + bv_);
        }
      }
    }
  } else if (MODE == 1) {
    float* C = (float*)(Cbase + (long)bz * sCz);
    const float* mk = (const float*)((const char*)maskb + (long)bz * sMz);
#pragma unroll
    for (int i = 0; i < 4; i++) {
#pragma unroll
      for (int j = 0; j < 4; j++) {
#pragma unroll
        for (int r = 0; r < 4; r++) {
          const long idx = (long)(row0 + i * 16 + r) * N + col0 + j * 16;
          C[idx] = acc[i][j][r] * scale + mk[idx];
        }
      }
    }
  } else {
    float* C = (float*)(Cbase + (long)bz * sCz);
#pragma unroll
    for (int i = 0; i < 4; i++) {
#pragma unroll
      for (int j = 0; j < 4; j++) {
#pragma unroll
        for (int r = 0; r < 4; r++) {
          C[(long)(row0 + i * 16 + r) * N + col0 + j * 16] = acc[i][j][r];
        }
      }
    }
  }
}

// ---------------- launch ----------------
extern "C" void kernel_launch(void* const* d_in, const int* in_sizes, int n_in,
                              void* d_out, int out_size, void* d_ws, size_t ws_size,
                              hipStream_t stream) {
  const float* hs = (const float*)d_in[0];
  const float* mask = (const float*)d_in[1];
  const float* Wq = (const float*)d_in[2];
  const float* bq = (const float*)d_in[3];
  const float* Wk = (const float*)d_in[4];
  const float* bk = (const float*)d_in[5];
  const float* Wv = (const float*)d_in[6];
  const float* bv = (const float*)d_in[7];
  float* out = (float*)d_out;

  char* ws = (char*)d_ws;
  uint16_t* hsb = (uint16_t*)ws;                  // [8192][1024] bf16   16MB
  uint16_t* WT = (uint16_t*)(ws + (16L << 20));   // [3][1024][1024]      6MB
  uint16_t* QKV = (uint16_t*)(ws + (22L << 20));  // [3][8192][1024]     48MB
  uint16_t* Vt = (uint16_t*)(ws + (70L << 20));   // [4][1024][2048]     16MB
  float* Sc = (float*)(ws + (86L << 20));         // [4][2048][2048] f32 64MB
  uint16_t* P = (uint16_t*)(ws + (150L << 20));   // [4][2048][2048]     32MB

  // 1) hs -> bf16
  cvt_f32_to_bf16<<<4096, 256, 0, stream>>>(hs, hsb);
  // 2) W -> W^T bf16 (x3)
  cvt_w_transpose<<<dim3(16, 8, 3), 64, 0, stream>>>(Wq, Wk, Wv, WT);
  // 3) projections: [8192x1024] x [1024x1024]^T(stored NT) -> Q,K,V bf16
  gemm_bt<0><<<dim3(64, 8, 3), 256, 0, stream>>>(
      hsb, 0L, WT, 2L << 20, 1024, 1024, (char*)QKV, 16L << 20,
      bq, bk, bv, nullptr, 0L, 0.f);
  // 4) V transpose per batch
  transpose_v<<<dim3(32, 16, 4), 256, 0, stream>>>(QKV + 2L * 8192 * 1024, Vt);
  // 5) scores = Q K^T / 32 + mask  (per batch)
  gemm_bt<1><<<dim3(16, 16, 4), 256, 0, stream>>>(
      QKV, 4L << 20, QKV + 8192L * 1024, 4L << 20, 1024, 2048, (char*)Sc, 16L << 20,
      nullptr, nullptr, nullptr, mask, 16L << 20, 0.03125f);
  // 6) softmax rows -> P bf16
  softmax_rows<<<8192, 256, 0, stream>>>(Sc, P);
  // 7) out = P V   (B operand = Vt, NT pattern), fp32 out
  gemm_bt<2><<<dim3(16, 8, 4), 256, 0, stream>>>(
      P, 8L << 20, Vt, 4L << 20, 2048, 1024, (char*)out, 8L << 20,
      nullptr, nullptr, nullptr, nullptr, 0L, 0.f);
}

// Round 4
// 225.834 us; speedup vs baseline: 1.1229x; 1.1229x over previous
//
#include <hip/hip_runtime.h>
#include <stdint.h>

typedef __attribute__((ext_vector_type(8))) short short8;
typedef __attribute__((ext_vector_type(8))) unsigned short u16x8;
typedef __attribute__((ext_vector_type(4))) float f32x4;

// round-to-nearest-even fp32 -> bf16 (finite inputs)
__device__ __forceinline__ uint16_t f2bf(float x) {
  uint32_t u = __float_as_uint(x);
  uint32_t r = (u + 0x7FFFu + ((u >> 16) & 1u)) >> 16;
  return (uint16_t)r;
}
__device__ __forceinline__ float bf2f(uint16_t x) {
  return __uint_as_float(((uint32_t)x) << 16);
}

// async global->LDS, 16B per lane. lds dest must be wave-uniform base (HW adds lane*16).
__device__ __forceinline__ void gl_lds16(const uint16_t* g, uint16_t* l) {
  __builtin_amdgcn_global_load_lds(
      (const __attribute__((address_space(1))) void*)g,
      (__attribute__((address_space(3))) void*)l, 16, 0, 0);
}

// ---------------- conversion kernels ----------------

__global__ __launch_bounds__(256) void cvt_f32_to_bf16(const float* __restrict__ in,
                                                       uint16_t* __restrict__ out) {
  long i = ((long)blockIdx.x * 256 + threadIdx.x) * 8;
  f32x4 v0 = *(const f32x4*)(in + i);
  f32x4 v1 = *(const f32x4*)(in + i + 4);
  u16x8 o;
  o[0] = f2bf(v0[0]); o[1] = f2bf(v0[1]); o[2] = f2bf(v0[2]); o[3] = f2bf(v0[3]);
  o[4] = f2bf(v1[0]); o[5] = f2bf(v1[1]); o[6] = f2bf(v1[2]); o[7] = f2bf(v1[3]);
  *(u16x8*)(out + i) = o;
}

// W [1024][1024] f32 -> WT [1024(n)][1024(k)] bf16 (3 matrices via blockIdx.z)
__global__ __launch_bounds__(64) void cvt_w_transpose(const float* __restrict__ W0,
                                                      const float* __restrict__ W1,
                                                      const float* __restrict__ W2,
                                                      uint16_t* __restrict__ WT) {
  const int z = blockIdx.z;
  const float* W = (z == 0) ? W0 : ((z == 1) ? W1 : W2);
  uint16_t* out = WT + (long)z * 1024 * 1024;
  const int n = blockIdx.x * 64 + threadIdx.x;  // column of W
  const int k0 = blockIdx.y * 128;
  for (int kk = 0; kk < 128; kk += 8) {
    u16x8 o;
#pragma unroll
    for (int j = 0; j < 8; j++) o[j] = f2bf(W[(long)(k0 + kk + j) * 1024 + n]);
    *(u16x8*)(out + (long)n * 1024 + k0 + kk) = o;
  }
}

// V [4*2048][1024] bf16 -> Vt [4][1024(d)][2048(s)] bf16
__global__ __launch_bounds__(256) void transpose_v(const uint16_t* __restrict__ V,
                                                   uint16_t* __restrict__ Vt) {
  __shared__ uint16_t tile[64][66];
  const int b = blockIdx.z;
  const int s0 = blockIdx.x * 64, d0 = blockIdx.y * 64;
  const int t = threadIdx.x;
  const int r = t >> 3, c = (t & 7) * 8;
  const uint16_t* Vb = V + (long)b * 2048 * 1024;
#pragma unroll
  for (int j = 0; j < 2; j++) {
    u16x8 v = *(const u16x8*)(Vb + (long)(s0 + r + 32 * j) * 1024 + d0 + c);
#pragma unroll
    for (int i = 0; i < 8; i++) tile[r + 32 * j][c + i] = v[i];
  }
  __syncthreads();
  uint16_t* Vtb = Vt + (long)b * 1024 * 2048;
#pragma unroll
  for (int j = 0; j < 2; j++) {
    const int d = r + 32 * j;
    u16x8 o;
#pragma unroll
    for (int i = 0; i < 8; i++) o[i] = tile[c + i][d];
    *(u16x8*)(Vtb + (long)(d0 + d) * 2048 + s0 + c) = o;
  }
}

// ---------------- softmax over rows of 2048 (bf16 in, bf16 out) ----------------
__global__ __launch_bounds__(256) void softmax_rows(const uint16_t* __restrict__ Sc,
                                                    uint16_t* __restrict__ P) {
  const long row = blockIdx.x;
  const uint16_t* src = Sc + row * 2048;
  const int t = threadIdx.x;
  u16x8 v = *(const u16x8*)(src + t * 8);
  float f[8];
#pragma unroll
  for (int i = 0; i < 8; i++) f[i] = bf2f(v[i]);
  float m = fmaxf(fmaxf(fmaxf(f[0], f[1]), fmaxf(f[2], f[3])),
                  fmaxf(fmaxf(f[4], f[5]), fmaxf(f[6], f[7])));
#pragma unroll
  for (int off = 32; off >= 1; off >>= 1) m = fmaxf(m, __shfl_xor(m, off));
  __shared__ float redm[4];
  __shared__ float reds[4];
  if ((t & 63) == 0) redm[t >> 6] = m;
  __syncthreads();
  m = fmaxf(fmaxf(redm[0], redm[1]), fmaxf(redm[2], redm[3]));
  float e[8];
#pragma unroll
  for (int i = 0; i < 8; i++) e[i] = __expf(f[i] - m);
  float s = 0.f;
#pragma unroll
  for (int i = 0; i < 8; i++) s += e[i];
#pragma unroll
  for (int off = 32; off >= 1; off >>= 1) s += __shfl_xor(s, off);
  if ((t & 63) == 0) reds[t >> 6] = s;
  __syncthreads();
  s = reds[0] + reds[1] + reds[2] + reds[3];
  const float inv = 1.0f / s;
  u16x8 o;
#pragma unroll
  for (int i = 0; i < 8; i++) o[i] = f2bf(e[i] * inv);
  *(u16x8*)(P + row * 2048 + t * 8) = o;
}

// ---------------- NT GEMM: C[M,N] = A[M,K] * B[N,K]^T ----------------
// 128x128 tile, BK=32, 4 waves, double-buffered LDS, ONE barrier per K-step:
//   sync (buf[cur] ready) -> issue stage(buf[cur^1], k+32) -> ds_read+MFMA on cur
// The global_load_lds latency is hidden under the 16 MFMAs; __syncthreads'
// implicit vmcnt(0) lands after compute.
// MODE 0: C = bf16(acc + bias[n])
// MODE 1: C = bf16(acc*scale + mask[idx])
// MODE 2: C = f32(acc)
template <int MODE>
__global__ __launch_bounds__(256) void gemm_bt(
    const uint16_t* __restrict__ Abase, long sAz,  // byte strides per blockIdx.z
    const uint16_t* __restrict__ Bbase, long sBz,
    int K, int N,
    char* __restrict__ Cbase, long sCz,
    const float* __restrict__ e0, const float* __restrict__ e1,
    const float* __restrict__ e2,
    const float* __restrict__ maskb, long sMz, float scale) {
  __shared__ uint16_t Al[2][128 * 32];
  __shared__ uint16_t Bl[2][128 * 32];
  const int t = threadIdx.x;
  const int lane = t & 63;
  const int w = t >> 6;
  const int bm = blockIdx.x, bn = blockIdx.y, bz = blockIdx.z;

  const uint16_t* A = (const uint16_t*)((const char*)Abase + (long)bz * sAz);
  const uint16_t* Bm = (const uint16_t*)((const char*)Bbase + (long)bz * sBz);

  // staging: 256 threads x 16B = 4KB per shot; tile is 8KB -> 2 shots each
  const int sr = t >> 2;         // row 0..63 within shot
  const int sc = (t & 3) * 8;    // bf16 element offset within 32-elem row
  const uint16_t* ga0 = A + (long)(bm * 128 + sr) * K + sc;
  const uint16_t* ga1 = A + (long)(bm * 128 + 64 + sr) * K + sc;
  const uint16_t* gb0 = Bm + (long)(bn * 128 + sr) * K + sc;
  const uint16_t* gb1 = Bm + (long)(bn * 128 + 64 + sr) * K + sc;

  f32x4 acc[4][4];
#pragma unroll
  for (int i = 0; i < 4; i++)
#pragma unroll
    for (int j = 0; j < 4; j++) acc[i][j] = (f32x4){0.f, 0.f, 0.f, 0.f};

  const int wm = w >> 1, wn = w & 1;
  const int fr = lane & 15, kg = lane >> 4;
  const int aoff = (wm * 64 + fr) * 32 + kg * 8;
  const int boff = (wn * 64 + fr) * 32 + kg * 8;

  // prologue: stage k0=0 into buf 0
  gl_lds16(ga0, Al[0] + w * 512);
  gl_lds16(ga1, Al[0] + 2048 + w * 512);
  gl_lds16(gb0, Bl[0] + w * 512);
  gl_lds16(gb1, Bl[0] + 2048 + w * 512);

  int cur = 0;
  for (int k0 = 0; k0 < K; k0 += 32) {
    __syncthreads();  // vmcnt(0): buf[cur] staging complete; also fences LDS reuse
    if (k0 + 32 < K) {
      const int nb = cur ^ 1, kn = k0 + 32;
      gl_lds16(ga0 + kn, Al[nb] + w * 512);
      gl_lds16(ga1 + kn, Al[nb] + 2048 + w * 512);
      gl_lds16(gb0 + kn, Bl[nb] + w * 512);
      gl_lds16(gb1 + kn, Bl[nb] + 2048 + w * 512);
    }
    const uint16_t* Ab = Al[cur];
    const uint16_t* Bb = Bl[cur];
    short8 a[4], b[4];
#pragma unroll
    for (int i = 0; i < 4; i++) a[i] = *(const short8*)(Ab + aoff + i * 16 * 32);
#pragma unroll
    for (int j = 0; j < 4; j++) b[j] = *(const short8*)(Bb + boff + j * 16 * 32);
#pragma unroll
    for (int i = 0; i < 4; i++)
#pragma unroll
      for (int j = 0; j < 4; j++)
        acc[i][j] = __builtin_amdgcn_mfma_f32_16x16x32_bf16(a[i], b[j], acc[i][j], 0, 0, 0);
    cur ^= 1;
  }

  // epilogue: C/D frag layout col = lane&15, row = (lane>>4)*4 + reg  [m89]
  const int row0 = bm * 128 + wm * 64 + (kg << 2);
  const int col0 = bn * 128 + wn * 64 + fr;

  if (MODE == 0) {
    const float* bias = (bz == 0) ? e0 : ((bz == 1) ? e1 : e2);
    uint16_t* C = (uint16_t*)(Cbase + (long)bz * sCz);
#pragma unroll
    for (int i = 0; i < 4; i++) {
#pragma unroll
      for (int j = 0; j < 4; j++) {
        const float bv_ = bias[col0 + j * 16];
#pragma unroll
        for (int r = 0; r < 4; r++) {
          C[(long)(row0 + i * 16 + r) * N + col0 + j * 16] = f2bf(acc[i][j][r] + bv_);
        }
      }
    }
  } else if (MODE == 1) {
    uint16_t* C = (uint16_t*)(Cbase + (long)bz * sCz);
    const float* mk = (const float*)((const char*)maskb + (long)bz * sMz);
#pragma unroll
    for (int i = 0; i < 4; i++) {
#pragma unroll
      for (int j = 0; j < 4; j++) {
#pragma unroll
        for (int r = 0; r < 4; r++) {
          const long idx = (long)(row0 + i * 16 + r) * N + col0 + j * 16;
          C[idx] = f2bf(acc[i][j][r] * scale + mk[idx]);
        }
      }
    }
  } else {
    float* C = (float*)(Cbase + (long)bz * sCz);
#pragma unroll
    for (int i = 0; i < 4; i++) {
#pragma unroll
      for (int j = 0; j < 4; j++) {
#pragma unroll
        for (int r = 0; r < 4; r++) {
          C[(long)(row0 + i * 16 + r) * N + col0 + j * 16] = acc[i][j][r];
        }
      }
    }
  }
}

// ---------------- launch ----------------
extern "C" void kernel_launch(void* const* d_in, const int* in_sizes, int n_in,
                              void* d_out, int out_size, void* d_ws, size_t ws_size,
                              hipStream_t stream) {
  const float* hs = (const float*)d_in[0];
  const float* mask = (const float*)d_in[1];
  const float* Wq = (const float*)d_in[2];
  const float* bq = (const float*)d_in[3];
  const float* Wk = (const float*)d_in[4];
  const float* bk = (const float*)d_in[5];
  const float* Wv = (const float*)d_in[6];
  const float* bv = (const float*)d_in[7];
  float* out = (float*)d_out;

  char* ws = (char*)d_ws;
  uint16_t* hsb = (uint16_t*)ws;                  // [8192][1024] bf16   16MB
  uint16_t* WT = (uint16_t*)(ws + (16L << 20));   // [3][1024][1024]      6MB
  uint16_t* QKV = (uint16_t*)(ws + (22L << 20));  // [3][8192][1024]     48MB
  uint16_t* Vt = (uint16_t*)(ws + (70L << 20));   // [4][1024][2048]     16MB
  uint16_t* Sc = (uint16_t*)(ws + (86L << 20));   // [4][2048][2048] bf16 32MB
  uint16_t* P = (uint16_t*)(ws + (118L << 20));   // [4][2048][2048] bf16 32MB

  // 1) hs -> bf16
  cvt_f32_to_bf16<<<4096, 256, 0, stream>>>(hs, hsb);
  // 2) W -> W^T bf16 (x3)
  cvt_w_transpose<<<dim3(16, 8, 3), 64, 0, stream>>>(Wq, Wk, Wv, WT);
  // 3) projections: [8192x1024] x [1024x1024]^T(stored NT) -> Q,K,V bf16
  gemm_bt<0><<<dim3(64, 8, 3), 256, 0, stream>>>(
      hsb, 0L, WT, 2L << 20, 1024, 1024, (char*)QKV, 16L << 20,
      bq, bk, bv, nullptr, 0L, 0.f);
  // 4) V transpose per batch
  transpose_v<<<dim3(32, 16, 4), 256, 0, stream>>>(QKV + 2L * 8192 * 1024, Vt);
  // 5) scores = bf16(Q K^T / 32 + mask)  (per batch)
  gemm_bt<1><<<dim3(16, 16, 4), 256, 0, stream>>>(
      QKV, 4L << 20, QKV + 8192L * 1024, 4L << 20, 1024, 2048, (char*)Sc, 8L << 20,
      nullptr, nullptr, nullptr, mask, 16L << 20, 0.03125f);
  // 6) softmax rows -> P bf16
  softmax_rows<<<8192, 256, 0, stream>>>(Sc, P);
  // 7) out = P V   (B operand = Vt, NT pattern), fp32 out
  gemm_bt<2><<<dim3(16, 8, 4), 256, 0, stream>>>(
      P, 8L << 20, Vt, 4L << 20, 2048, 1024, (char*)out, 8L << 20,
      nullptr, nullptr, nullptr, nullptr, 0L, 0.f);
}

// Round 6
// 204.664 us; speedup vs baseline: 1.2391x; 1.1034x over previous
//
#include <hip/hip_runtime.h>
#include <stdint.h>

typedef __attribute__((ext_vector_type(8))) short short8;
typedef __attribute__((ext_vector_type(8))) unsigned short u16x8;
typedef __attribute__((ext_vector_type(4))) float f32x4;

// round-to-nearest-even fp32 -> bf16 (finite inputs)
__device__ __forceinline__ uint16_t f2bf(float x) {
  uint32_t u = __float_as_uint(x);
  uint32_t r = (u + 0x7FFFu + ((u >> 16) & 1u)) >> 16;
  return (uint16_t)r;
}
__device__ __forceinline__ float bf2f(uint16_t x) {
  return __uint_as_float(((uint32_t)x) << 16);
}

// async global->LDS, 16B per lane. LDS dest = wave-uniform base (HW adds lane*16).
__device__ __forceinline__ void gl_lds16(const uint16_t* g, void* l) {
  __builtin_amdgcn_global_load_lds(
      (const __attribute__((address_space(1))) void*)g,
      (__attribute__((address_space(3))) void*)l, 16, 0, 0);
}

// ---------------- conversion kernels ----------------

__global__ __launch_bounds__(256) void cvt_f32_to_bf16(const float* __restrict__ in,
                                                       uint16_t* __restrict__ out) {
  long i = ((long)blockIdx.x * 256 + threadIdx.x) * 8;
  f32x4 v0 = *(const f32x4*)(in + i);
  f32x4 v1 = *(const f32x4*)(in + i + 4);
  u16x8 o;
  o[0] = f2bf(v0[0]); o[1] = f2bf(v0[1]); o[2] = f2bf(v0[2]); o[3] = f2bf(v0[3]);
  o[4] = f2bf(v1[0]); o[5] = f2bf(v1[1]); o[6] = f2bf(v1[2]); o[7] = f2bf(v1[3]);
  *(u16x8*)(out + i) = o;
}

// W [1024][1024] f32 -> WT [1024(n)][1024(k)] bf16 (3 matrices via blockIdx.z)
__global__ __launch_bounds__(64) void cvt_w_transpose(const float* __restrict__ W0,
                                                      const float* __restrict__ W1,
                                                      const float* __restrict__ W2,
                                                      uint16_t* __restrict__ WT) {
  const int z = blockIdx.z;
  const float* W = (z == 0) ? W0 : ((z == 1) ? W1 : W2);
  uint16_t* out = WT + (long)z * 1024 * 1024;
  const int n = blockIdx.x * 64 + threadIdx.x;
  const int k0 = blockIdx.y * 128;
  for (int kk = 0; kk < 128; kk += 8) {
    u16x8 o;
#pragma unroll
    for (int j = 0; j < 8; j++) o[j] = f2bf(W[(long)(k0 + kk + j) * 1024 + n]);
    *(u16x8*)(out + (long)n * 1024 + k0 + kk) = o;
  }
}

// V [4*2048][1024] bf16 -> Vt [4][1024(d)][2048(s)] bf16
__global__ __launch_bounds__(256) void transpose_v(const uint16_t* __restrict__ V,
                                                   uint16_t* __restrict__ Vt) {
  __shared__ uint16_t tile[64][66];
  const int b = blockIdx.z;
  const int s0 = blockIdx.x * 64, d0 = blockIdx.y * 64;
  const int t = threadIdx.x;
  const int r = t >> 3, c = (t & 7) * 8;
  const uint16_t* Vb = V + (long)b * 2048 * 1024;
#pragma unroll
  for (int j = 0; j < 2; j++) {
    u16x8 v = *(const u16x8*)(Vb + (long)(s0 + r + 32 * j) * 1024 + d0 + c);
#pragma unroll
    for (int i = 0; i < 8; i++) tile[r + 32 * j][c + i] = v[i];
  }
  __syncthreads();
  uint16_t* Vtb = Vt + (long)b * 1024 * 2048;
#pragma unroll
  for (int j = 0; j < 2; j++) {
    const int d = r + 32 * j;
    u16x8 o;
#pragma unroll
    for (int i = 0; i < 8; i++) o[i] = tile[c + i][d];
    *(u16x8*)(Vtb + (long)(d0 + d) * 2048 + s0 + c) = o;
  }
}

// ---------------- row sum of E -> 1/l ----------------
__global__ __launch_bounds__(256) void rowsum_inv(const uint16_t* __restrict__ E,
                                                  float* __restrict__ invl) {
  const long row = blockIdx.x;
  const uint16_t* src = E + row * 2048;
  const int t = threadIdx.x;
  u16x8 v = *(const u16x8*)(src + t * 8);
  float s = 0.f;
#pragma unroll
  for (int i = 0; i < 8; i++) s += bf2f(v[i]);
#pragma unroll
  for (int off = 32; off >= 1; off >>= 1) s += __shfl_xor(s, off);
  __shared__ float red[4];
  if ((t & 63) == 0) red[t >> 6] = s;
  __syncthreads();
  if (t == 0) {
    invl[row] = 1.0f / (red[0] + red[1] + red[2] + red[3]);
  }
}

// ============ 256x256 8-phase NT GEMM: C[M,N] = A[M,K]*B[N,K]^T ============
// BK=64, 8 waves (2M x 4N), per-wave 128x64 output = acc[8][4] f32x4.
// LDS 128KB: dbuf d at d*65536: A 32KB then B 32KB. XOR-swizzle (row&7)<<4 on
// 16B slots; global_load_lds writes linearly, so the global SOURCE address is
// inverse-swizzled per-thread (rule #21) and ds_reads apply the same XOR.
// Per K-tile: 4 phases, each {issue 2 gl_lds of tile t+1 | ds_read quadrant |
// barrier | lgkmcnt(0) | setprio(1) 16 MFMA setprio(0) | barrier}; counted
// vmcnt(2) once per tile at phase 0 (next tile's first 2 loads stay in flight).
// MODE 0: C = bf16(acc + bias[n]);  MODE 1: C = bf16(exp(acc*scale + mask))
template <int MODE>
__global__ __launch_bounds__(512, 2) void gemm256(
    const uint16_t* __restrict__ Abase, long sAz,
    const uint16_t* __restrict__ Bbase, long sBz,
    int K, int N,
    char* __restrict__ Cbase, long sCz,
    const float* __restrict__ e0, const float* __restrict__ e1,
    const float* __restrict__ e2,
    const float* __restrict__ maskb, long sMz, float scale) {
  __shared__ __align__(16) char lds[131072];
  const int t = threadIdx.x;
  const int lane = t & 63;
  const int w = t >> 6;
  const int bm = blockIdx.x, bn = blockIdx.y, bz = blockIdx.z;
  const uint16_t* A = (const uint16_t*)((const char*)Abase + (long)bz * sAz);
  const uint16_t* B = (const uint16_t*)((const char*)Bbase + (long)bz * sBz);

  // stage: shot s covers LDS rows [s*64, s*64+64) of a 256x64 tile. Thread t's
  // 16B lands at D = s*8192 + t*16 -> row' = s*64 + (t>>3),
  // colbyte' = ((t&7)*16) ^ ((row'&7)<<4)  (inverse of the read swizzle).
  const int srow = t >> 3;
  const int scol = ((((t & 7) * 16) ^ ((srow & 7) << 4)) >> 1);  // bf16 elems
  const uint16_t* gA[4];
  const uint16_t* gB[4];
#pragma unroll
  for (int s = 0; s < 4; s++) {
    gA[s] = A + (long)(bm * 256 + s * 64 + srow) * K + scol;
    gB[s] = B + (long)(bn * 256 + s * 64 + srow) * K + scol;
  }

  const int wm = w >> 2, wn = w & 3;
  const int fr = lane & 15, kg = lane >> 4;
  const int X = (fr & 7) << 4;                       // swizzle mask (bits 4-6)
  const int aRow = (wm * 128 + fr) * 128 + kg * 16;  // + i*2048 + ks*64, ^X
  const int bRow = (wn * 64 + fr) * 128 + kg * 16;

  f32x4 acc[8][4];
#pragma unroll
  for (int i = 0; i < 8; i++)
#pragma unroll
    for (int j = 0; j < 4; j++) acc[i][j] = (f32x4){0.f, 0.f, 0.f, 0.f};

  short8 aR[4][2], bR[2][2];
  const int NT = K >> 6;

#define ARD(off, i, ks) (*(const short8*)(lds + (off) + ((aRow + (i) * 2048 + (ks) * 64) ^ X)))
#define BRD(off, j, ks) (*(const short8*)(lds + 32768 + (off) + ((bRow + (j) * 2048 + (ks) * 64) ^ X)))
#define STG_A01(off, ko) { gl_lds16(gA[0] + (ko), lds + (off) + w * 1024); \
                           gl_lds16(gA[1] + (ko), lds + (off) + 8192 + w * 1024); }
#define STG_A23(off, ko) { gl_lds16(gA[2] + (ko), lds + (off) + 16384 + w * 1024); \
                           gl_lds16(gA[3] + (ko), lds + (off) + 24576 + w * 1024); }
#define STG_B01(off, ko) { gl_lds16(gB[0] + (ko), lds + 32768 + (off) + w * 1024); \
                           gl_lds16(gB[1] + (ko), lds + 32768 + (off) + 8192 + w * 1024); }
#define STG_B23(off, ko) { gl_lds16(gB[2] + (ko), lds + 32768 + (off) + 16384 + w * 1024); \
                           gl_lds16(gB[3] + (ko), lds + 32768 + (off) + 24576 + w * 1024); }
#define LGKM0 { asm volatile("s_waitcnt lgkmcnt(0)" ::: "memory"); __builtin_amdgcn_sched_barrier(0); }
#define MFMA16(I0, J0)                                                            \
  __builtin_amdgcn_s_setprio(1);                                                  \
  _Pragma("unroll") for (int i = 0; i < 4; i++)                                   \
  _Pragma("unroll") for (int j = 0; j < 2; j++)                                   \
  _Pragma("unroll") for (int ks = 0; ks < 2; ks++)                                \
    acc[(I0) + i][(J0) + j] = __builtin_amdgcn_mfma_f32_16x16x32_bf16(            \
        aR[i][ks], bR[j][ks], acc[(I0) + i][(J0) + j], 0, 0, 0);                  \
  __builtin_amdgcn_s_setprio(0);

  // prologue: tile 0 -> buf 0
  STG_A01(0, 0); STG_A23(0, 0); STG_B01(0, 0); STG_B23(0, 0);

  int curo = 0;
  for (int tt = 0; tt < NT - 1; ++tt) {
    const int nxto = curo ^ 65536;
    const int ko = (tt + 1) << 6;
    // ---- phase 0: quadrant (i0-3, j0-1)
    STG_A01(nxto, ko);
    asm volatile("s_waitcnt vmcnt(2)" ::: "memory");  // tile tt's 8 loads done
    __builtin_amdgcn_s_barrier();
    __builtin_amdgcn_sched_barrier(0);
#pragma unroll
    for (int i = 0; i < 4; i++) { aR[i][0] = ARD(curo, i, 0); aR[i][1] = ARD(curo, i, 1); }
#pragma unroll
    for (int j = 0; j < 2; j++) { bR[j][0] = BRD(curo, j, 0); bR[j][1] = BRD(curo, j, 1); }
    LGKM0;
    MFMA16(0, 0);
    __builtin_amdgcn_s_barrier();
    // ---- phase 1: quadrant (i0-3, j2-3)
    STG_A23(nxto, ko);
#pragma unroll
    for (int j = 0; j < 2; j++) { bR[j][0] = BRD(curo, 2 + j, 0); bR[j][1] = BRD(curo, 2 + j, 1); }
    __builtin_amdgcn_s_barrier();
    LGKM0;
    MFMA16(0, 2);
    __builtin_amdgcn_s_barrier();
    // ---- phase 2: quadrant (i4-7, j2-3)
    STG_B01(nxto, ko);
#pragma unroll
    for (int i = 0; i < 4; i++) { aR[i][0] = ARD(curo, 4 + i, 0); aR[i][1] = ARD(curo, 4 + i, 1); }
    __builtin_amdgcn_s_barrier();
    LGKM0;
    MFMA16(4, 2);
    __builtin_amdgcn_s_barrier();
    // ---- phase 3: quadrant (i4-7, j0-1)
    STG_B23(nxto, ko);
#pragma unroll
    for (int j = 0; j < 2; j++) { bR[j][0] = BRD(curo, j, 0); bR[j][1] = BRD(curo, j, 1); }
    __builtin_amdgcn_s_barrier();
    LGKM0;
    MFMA16(4, 0);
    __builtin_amdgcn_s_barrier();
    curo = nxto;
  }
  // ---- tail tile (no prefetch): drain all loads once
  asm volatile("s_waitcnt vmcnt(0)" ::: "memory");
  __builtin_amdgcn_s_barrier();
  __builtin_amdgcn_sched_barrier(0);
#pragma unroll
  for (int i = 0; i < 4; i++) { aR[i][0] = ARD(curo, i, 0); aR[i][1] = ARD(curo, i, 1); }
#pragma unroll
  for (int j = 0; j < 2; j++) { bR[j][0] = BRD(curo, j, 0); bR[j][1] = BRD(curo, j, 1); }
  LGKM0;
  MFMA16(0, 0);
#pragma unroll
  for (int j = 0; j < 2; j++) { bR[j][0] = BRD(curo, 2 + j, 0); bR[j][1] = BRD(curo, 2 + j, 1); }
  LGKM0;
  MFMA16(0, 2);
#pragma unroll
  for (int i = 0; i < 4; i++) { aR[i][0] = ARD(curo, 4 + i, 0); aR[i][1] = ARD(curo, 4 + i, 1); }
  LGKM0;
  MFMA16(4, 2);
#pragma unroll
  for (int j = 0; j < 2; j++) { bR[j][0] = BRD(curo, j, 0); bR[j][1] = BRD(curo, j, 1); }
  LGKM0;
  MFMA16(4, 0);

  // ---- epilogue: D frag col = col0 + j*16 + ... (col=fr), row = kg*4 + reg
  const int row0 = bm * 256 + wm * 128 + (kg << 2);
  const int col0 = bn * 256 + wn * 64 + fr;
  if (MODE == 0) {
    const float* bias = (bz == 0) ? e0 : ((bz == 1) ? e1 : e2);
    uint16_t* C = (uint16_t*)(Cbase + (long)bz * sCz);
#pragma unroll
    for (int i = 0; i < 8; i++) {
#pragma unroll
      for (int j = 0; j < 4; j++) {
        const float bv_ = bias[col0 + j * 16];
#pragma unroll
        for (int r = 0; r < 4; r++) {
          C[(long)(row0 + i * 16 + r) * N + col0 + j * 16] = f2bf(acc[i][j][r] + bv_);
        }
      }
    }
  } else {
    uint16_t* C = (uint16_t*)(Cbase + (long)bz * sCz);
    const float* mk = (const float*)((const char*)maskb + (long)bz * sMz);
#pragma unroll
    for (int i = 0; i < 8; i++) {
#pragma unroll
      for (int j = 0; j < 4; j++) {
#pragma unroll
        for (int r = 0; r < 4; r++) {
          const long idx = (long)(row0 + i * 16 + r) * N + col0 + j * 16;
          C[idx] = f2bf(__expf(acc[i][j][r] * scale + mk[idx]));
        }
      }
    }
  }
#undef ARD
#undef BRD
#undef STG_A01
#undef STG_A23
#undef STG_B01
#undef STG_B23
#undef LGKM0
#undef MFMA16
}

// ---------------- PV GEMM (128x128 2-phase, proven): out = (E*Vt^T)*invl ----
__global__ __launch_bounds__(256) void gemm_pv(
    const uint16_t* __restrict__ Abase, long sAz,
    const uint16_t* __restrict__ Bbase, long sBz,
    int K, int N,
    float* __restrict__ Cbase, long sCzf,
    const float* __restrict__ rowinv) {
  __shared__ uint16_t Al[2][128 * 32];
  __shared__ uint16_t Bl[2][128 * 32];
  const int t = threadIdx.x;
  const int lane = t & 63;
  const int w = t >> 6;
  const int bm = blockIdx.x, bn = blockIdx.y, bz = blockIdx.z;

  const uint16_t* A = (const uint16_t*)((const char*)Abase + (long)bz * sAz);
  const uint16_t* Bm = (const uint16_t*)((const char*)Bbase + (long)bz * sBz);

  const int sr = t >> 2;
  const int sc = (t & 3) * 8;
  const uint16_t* ga0 = A + (long)(bm * 128 + sr) * K + sc;
  const uint16_t* ga1 = A + (long)(bm * 128 + 64 + sr) * K + sc;
  const uint16_t* gb0 = Bm + (long)(bn * 128 + sr) * K + sc;
  const uint16_t* gb1 = Bm + (long)(bn * 128 + 64 + sr) * K + sc;

  f32x4 acc[4][4];
#pragma unroll
  for (int i = 0; i < 4; i++)
#pragma unroll
    for (int j = 0; j < 4; j++) acc[i][j] = (f32x4){0.f, 0.f, 0.f, 0.f};

  const int wm = w >> 1, wn = w & 1;
  const int fr = lane & 15, kg = lane >> 4;
  const int aoff = (wm * 64 + fr) * 32 + kg * 8;
  const int boff = (wn * 64 + fr) * 32 + kg * 8;

  gl_lds16(ga0, Al[0] + w * 512);
  gl_lds16(ga1, Al[0] + 2048 + w * 512);
  gl_lds16(gb0, Bl[0] + w * 512);
  gl_lds16(gb1, Bl[0] + 2048 + w * 512);

  int cur = 0;
  for (int k0 = 0; k0 < K; k0 += 32) {
    __syncthreads();
    if (k0 + 32 < K) {
      const int nb = cur ^ 1, kn = k0 + 32;
      gl_lds16(ga0 + kn, Al[nb] + w * 512);
      gl_lds16(ga1 + kn, Al[nb] + 2048 + w * 512);
      gl_lds16(gb0 + kn, Bl[nb] + w * 512);
      gl_lds16(gb1 + kn, Bl[nb] + 2048 + w * 512);
    }
    const uint16_t* Ab = Al[cur];
    const uint16_t* Bb = Bl[cur];
    short8 a[4], b[4];
#pragma unroll
    for (int i = 0; i < 4; i++) a[i] = *(const short8*)(Ab + aoff + i * 16 * 32);
#pragma unroll
    for (int j = 0; j < 4; j++) b[j] = *(const short8*)(Bb + boff + j * 16 * 32);
#pragma unroll
    for (int i = 0; i < 4; i++)
#pragma unroll
      for (int j = 0; j < 4; j++)
        acc[i][j] = __builtin_amdgcn_mfma_f32_16x16x32_bf16(a[i], b[j], acc[i][j], 0, 0, 0);
    cur ^= 1;
  }

  const int row0 = bm * 128 + wm * 64 + (kg << 2);
  const int col0 = bn * 128 + wn * 64 + fr;
  float* C = Cbase + (long)bz * sCzf;
  const float* ri = rowinv + (long)bz * 2048;
#pragma unroll
  for (int i = 0; i < 4; i++) {
#pragma unroll
    for (int j = 0; j < 4; j++) {
#pragma unroll
      for (int r = 0; r < 4; r++) {
        const int row = row0 + i * 16 + r;
        C[(long)row * N + col0 + j * 16] = acc[i][j][r] * ri[row];
      }
    }
  }
}

// ---------------- launch ----------------
extern "C" void kernel_launch(void* const* d_in, const int* in_sizes, int n_in,
                              void* d_out, int out_size, void* d_ws, size_t ws_size,
                              hipStream_t stream) {
  const float* hs = (const float*)d_in[0];
  const float* mask = (const float*)d_in[1];
  const float* Wq = (const float*)d_in[2];
  const float* bq = (const float*)d_in[3];
  const float* Wk = (const float*)d_in[4];
  const float* bk = (const float*)d_in[5];
  const float* Wv = (const float*)d_in[6];
  const float* bv = (const float*)d_in[7];
  float* out = (float*)d_out;

  char* ws = (char*)d_ws;
  uint16_t* hsb = (uint16_t*)ws;                  // [8192][1024] bf16    16MB
  uint16_t* WT = (uint16_t*)(ws + (16L << 20));   // [3][1024][1024]       6MB
  uint16_t* QKV = (uint16_t*)(ws + (22L << 20));  // [3][8192][1024]      48MB
  uint16_t* Vt = (uint16_t*)(ws + (70L << 20));   // [4][1024(d)][2048]   16MB
  uint16_t* E = (uint16_t*)(ws + (86L << 20));    // [4][2048][2048] bf16 32MB
  float* invl = (float*)(ws + (118L << 20));      // [8192] f32           32KB

  // 1) hs -> bf16
  cvt_f32_to_bf16<<<4096, 256, 0, stream>>>(hs, hsb);
  // 2) W -> W^T bf16 (x3)
  cvt_w_transpose<<<dim3(16, 8, 3), 64, 0, stream>>>(Wq, Wk, Wv, WT);
  // 3) projections (8-phase 256x256): Q,K,V bf16 with bias
  gemm256<0><<<dim3(32, 4, 3), 512, 0, stream>>>(
      hsb, 0L, WT, 2L << 20, 1024, 1024, (char*)QKV, 16L << 20,
      bq, bk, bv, nullptr, 0L, 0.f);
  // 4) V transpose per batch
  transpose_v<<<dim3(32, 16, 4), 256, 0, stream>>>(QKV + 2L * 8192 * 1024, Vt);
  // 5) E = bf16(exp(Q K^T / 32 + mask))   (8-phase 256x256, exp fused)
  gemm256<1><<<dim3(8, 8, 4), 512, 0, stream>>>(
      QKV, 4L << 20, QKV + 8192L * 1024, 4L << 20, 1024, 2048, (char*)E, 8L << 20,
      nullptr, nullptr, nullptr, mask, 16L << 20, 0.03125f);
  // 6) inv row sums of E
  rowsum_inv<<<8192, 256, 0, stream>>>(E, invl);
  // 7) out = (E Vt^T) * invl  (f32)
  gemm_pv<<<dim3(16, 8, 4), 256, 0, stream>>>(
      E, 8L << 20, Vt, 4L << 20, 2048, 1024, out, 2048L * 1024, invl);
}

// Round 7
// 191.485 us; speedup vs baseline: 1.3244x; 1.0688x over previous
//
#include <hip/hip_runtime.h>
#include <stdint.h>

typedef __attribute__((ext_vector_type(8))) short short8;
typedef __attribute__((ext_vector_type(8))) unsigned short u16x8;
typedef __attribute__((ext_vector_type(4))) float f32x4;

__device__ __forceinline__ uint16_t f2bf(float x) {
  uint32_t u = __float_as_uint(x);
  uint32_t r = (u + 0x7FFFu + ((u >> 16) & 1u)) >> 16;
  return (uint16_t)r;
}
__device__ __forceinline__ float bf2f(uint16_t x) {
  return __uint_as_float(((uint32_t)x) << 16);
}

// async global->LDS, 16B per lane. LDS dest = wave-uniform base (HW adds lane*16).
__device__ __forceinline__ void gl_lds16(const uint16_t* g, void* l) {
  __builtin_amdgcn_global_load_lds(
      (const __attribute__((address_space(1))) void*)g,
      (__attribute__((address_space(3))) void*)l, 16, 0, 0);
}

// ---------------- conversion kernels ----------------

__global__ __launch_bounds__(256) void cvt_f32_to_bf16(const float* __restrict__ in,
                                                       uint16_t* __restrict__ out) {
  long i = ((long)blockIdx.x * 256 + threadIdx.x) * 8;
  f32x4 v0 = *(const f32x4*)(in + i);
  f32x4 v1 = *(const f32x4*)(in + i + 4);
  u16x8 o;
  o[0] = f2bf(v0[0]); o[1] = f2bf(v0[1]); o[2] = f2bf(v0[2]); o[3] = f2bf(v0[3]);
  o[4] = f2bf(v1[0]); o[5] = f2bf(v1[1]); o[6] = f2bf(v1[2]); o[7] = f2bf(v1[3]);
  *(u16x8*)(out + i) = o;
}

// W [1024][1024] f32 -> WT [1024(n)][1024(k)] bf16 (3 matrices via blockIdx.z)
__global__ __launch_bounds__(64) void cvt_w_transpose(const float* __restrict__ W0,
                                                      const float* __restrict__ W1,
                                                      const float* __restrict__ W2,
                                                      uint16_t* __restrict__ WT) {
  const int z = blockIdx.z;
  const float* W = (z == 0) ? W0 : ((z == 1) ? W1 : W2);
  uint16_t* out = WT + (long)z * 1024 * 1024;
  const int n = blockIdx.x * 64 + threadIdx.x;
  const int k0 = blockIdx.y * 128;
  for (int kk = 0; kk < 128; kk += 8) {
    u16x8 o;
#pragma unroll
    for (int j = 0; j < 8; j++) o[j] = f2bf(W[(long)(k0 + kk + j) * 1024 + n]);
    *(u16x8*)(out + (long)n * 1024 + k0 + kk) = o;
  }
}

// V [4*2048][1024] bf16 -> Vt [4][1024(d)][2048(s)] bf16
__global__ __launch_bounds__(256) void transpose_v(const uint16_t* __restrict__ V,
                                                   uint16_t* __restrict__ Vt) {
  __shared__ uint16_t tile[64][66];
  const int b = blockIdx.z;
  const int s0 = blockIdx.x * 64, d0 = blockIdx.y * 64;
  const int t = threadIdx.x;
  const int r = t >> 3, c = (t & 7) * 8;
  const uint16_t* Vb = V + (long)b * 2048 * 1024;
#pragma unroll
  for (int j = 0; j < 2; j++) {
    u16x8 v = *(const u16x8*)(Vb + (long)(s0 + r + 32 * j) * 1024 + d0 + c);
#pragma unroll
    for (int i = 0; i < 8; i++) tile[r + 32 * j][c + i] = v[i];
  }
  __syncthreads();
  uint16_t* Vtb = Vt + (long)b * 1024 * 2048;
#pragma unroll
  for (int j = 0; j < 2; j++) {
    const int d = r + 32 * j;
    u16x8 o;
#pragma unroll
    for (int i = 0; i < 8; i++) o[i] = tile[c + i][d];
    *(u16x8*)(Vtb + (long)(d0 + d) * 2048 + s0 + c) = o;
  }
}

// ---------------- row sum of E -> 1/l ----------------
__global__ __launch_bounds__(256) void rowsum_inv(const uint16_t* __restrict__ E,
                                                  float* __restrict__ invl) {
  const long row = blockIdx.x;
  const uint16_t* src = E + row * 2048;
  const int t = threadIdx.x;
  u16x8 v = *(const u16x8*)(src + t * 8);
  float s = 0.f;
#pragma unroll
  for (int i = 0; i < 8; i++) s += bf2f(v[i]);
#pragma unroll
  for (int off = 32; off >= 1; off >>= 1) s += __shfl_xor(s, off);
  __shared__ float red[4];
  if ((t & 63) == 0) red[t >> 6] = s;
  __syncthreads();
  if (t == 0) {
    invl[row] = 1.0f / (red[0] + red[1] + red[2] + red[3]);
  }
}

// ============ generalized 8-wave NT GEMM: C[M,N] = A[M,K]*B[N,K]^T ==========
// AI=8: BM=256, 4 phases/K-tile of 16 MFMA (proven gemm256 schedule).
// AI=4: BM=128, 2 phases/K-tile of 16 MFMA, 6 loads/tile, vmcnt(4).
// BN=256, BK=64, 8 waves (2M x 4N). LDS dbuf: A (BM*128 B) then B (32KB).
// XOR-swizzle (row&7)<<4 on 16B slots; gl_lds writes linearly -> global source
// is inverse-swizzled; ds_reads apply the same XOR (rule #21).
// MODE 0 (AI=4): fused QKV proj. B=WT[3072][1024]; z=bn>>2 selects output
//   slab (sCz stride) and bias (e0/e1/e2). C = bf16(acc + bias).
// MODE 1 (AI=8): C = bf16(exp(acc*scale + mask)), batch via blockIdx.z.
// MODE 2 (AI=4): C = f32(acc * rowinv[row]), batch via blockIdx.z.
template <int MODE, int AI>
__global__ __launch_bounds__(512, 2) void gemmX(
    const uint16_t* __restrict__ Abase, long sAz,
    const uint16_t* __restrict__ Bbase, long sBz,
    int K, int N,
    char* __restrict__ Cbase, long sCz,
    const float* __restrict__ e0, const float* __restrict__ e1,
    const float* __restrict__ e2,
    const float* __restrict__ maskb, long sMz, float scale,
    const float* __restrict__ rowinv) {
  constexpr int BM = AI * 32;
  constexpr int ABYTES = BM * 128;          // A region bytes per buffer
  constexpr int BUFB = ABYTES + 32768;      // per-dbuf stride
  __shared__ __align__(16) char lds[2 * BUFB];
  const int t = threadIdx.x;
  const int lane = t & 63;
  const int w = t >> 6;
  const int bm = blockIdx.x, bn = blockIdx.y, bz = blockIdx.z;
  const uint16_t* A = (const uint16_t*)((const char*)Abase + (long)bz * sAz);
  const uint16_t* B = (const uint16_t*)((const char*)Bbase + (long)bz * sBz);

  // staging geometry: shot = 512 threads x 16B = 8KB = 64 rows x 128B.
  const int srow = t >> 3;
  const int scol = ((((t & 7) * 16) ^ ((srow & 7) << 4)) >> 1);  // bf16 elems
  const uint16_t* gA[4];
  const uint16_t* gB[4];
#pragma unroll
  for (int s = 0; s < 4; s++) {
    gA[s] = A + (long)(bm * BM + (s % (AI / 2)) * 64 + srow) * K + scol;
    gB[s] = B + (long)(bn * 256 + s * 64 + srow) * K + scol;
  }

  const int wm = w >> 2, wn = w & 3;
  const int fr = lane & 15, kg = lane >> 4;
  const int X = (fr & 7) << 4;
  const int aRow = (wm * (AI * 16) + fr) * 128 + kg * 16;
  const int bRow = (wn * 64 + fr) * 128 + kg * 16;

  f32x4 acc[AI][4];
#pragma unroll
  for (int i = 0; i < AI; i++)
#pragma unroll
    for (int j = 0; j < 4; j++) acc[i][j] = (f32x4){0.f, 0.f, 0.f, 0.f};

  short8 aR[4][2], bR[2][2];
  const int NT = K >> 6;

#define ARD(off, i, ks) (*(const short8*)(lds + (off) + ((aRow + (i) * 2048 + (ks) * 64) ^ X)))
#define BRD(off, j, ks) (*(const short8*)(lds + ABYTES + (off) + ((bRow + (j) * 2048 + (ks) * 64) ^ X)))
#define STG_A01(off, ko) { gl_lds16(gA[0] + (ko), lds + (off) + w * 1024); \
                           gl_lds16(gA[1] + (ko), lds + (off) + 8192 + w * 1024); }
#define STG_A23(off, ko) { gl_lds16(gA[2] + (ko), lds + (off) + 16384 + w * 1024); \
                           gl_lds16(gA[3] + (ko), lds + (off) + 24576 + w * 1024); }
#define STG_B01(off, ko) { gl_lds16(gB[0] + (ko), lds + ABYTES + (off) + w * 1024); \
                           gl_lds16(gB[1] + (ko), lds + ABYTES + (off) + 8192 + w * 1024); }
#define STG_B23(off, ko) { gl_lds16(gB[2] + (ko), lds + ABYTES + (off) + 16384 + w * 1024); \
                           gl_lds16(gB[3] + (ko), lds + ABYTES + (off) + 24576 + w * 1024); }
#define LGKM0 { asm volatile("s_waitcnt lgkmcnt(0)" ::: "memory"); __builtin_amdgcn_sched_barrier(0); }
#define MFMA16(I0, J0)                                                            \
  __builtin_amdgcn_s_setprio(1);                                                  \
  _Pragma("unroll") for (int i = 0; i < 4; i++)                                   \
  _Pragma("unroll") for (int j = 0; j < 2; j++)                                   \
  _Pragma("unroll") for (int ks = 0; ks < 2; ks++)                                \
    acc[(I0) + i][(J0) + j] = __builtin_amdgcn_mfma_f32_16x16x32_bf16(            \
        aR[i][ks], bR[j][ks], acc[(I0) + i][(J0) + j], 0, 0, 0);                  \
  __builtin_amdgcn_s_setprio(0);

  // prologue: tile 0 -> buf 0
  if constexpr (AI == 8) { STG_A01(0, 0); STG_A23(0, 0); }
  else                   { STG_A01(0, 0); }
  STG_B01(0, 0); STG_B23(0, 0);

  int curo = 0;
  for (int tt = 0; tt < NT - 1; ++tt) {
    const int nxto = curo ^ BUFB;
    const int ko = (tt + 1) << 6;
    if constexpr (AI == 8) {
      // ---- phase 0: (i0-3, j0-1)
      STG_A01(nxto, ko);
      asm volatile("s_waitcnt vmcnt(2)" ::: "memory");
      __builtin_amdgcn_s_barrier();
      __builtin_amdgcn_sched_barrier(0);
#pragma unroll
      for (int i = 0; i < 4; i++) { aR[i][0] = ARD(curo, i, 0); aR[i][1] = ARD(curo, i, 1); }
#pragma unroll
      for (int j = 0; j < 2; j++) { bR[j][0] = BRD(curo, j, 0); bR[j][1] = BRD(curo, j, 1); }
      LGKM0;
      MFMA16(0, 0);
      __builtin_amdgcn_s_barrier();
      // ---- phase 1: (i0-3, j2-3)
      STG_A23(nxto, ko);
#pragma unroll
      for (int j = 0; j < 2; j++) { bR[j][0] = BRD(curo, 2 + j, 0); bR[j][1] = BRD(curo, 2 + j, 1); }
      __builtin_amdgcn_s_barrier();
      LGKM0;
      MFMA16(0, 2);
      __builtin_amdgcn_s_barrier();
      // ---- phase 2: (i4-7, j2-3)
      STG_B01(nxto, ko);
#pragma unroll
      for (int i = 0; i < 4; i++) { aR[i][0] = ARD(curo, 4 + i, 0); aR[i][1] = ARD(curo, 4 + i, 1); }
      __builtin_amdgcn_s_barrier();
      LGKM0;
      MFMA16(4, 2);
      __builtin_amdgcn_s_barrier();
      // ---- phase 3: (i4-7, j0-1)
      STG_B23(nxto, ko);
#pragma unroll
      for (int j = 0; j < 2; j++) { bR[j][0] = BRD(curo, j, 0); bR[j][1] = BRD(curo, j, 1); }
      __builtin_amdgcn_s_barrier();
      LGKM0;
      MFMA16(4, 0);
      __builtin_amdgcn_s_barrier();
    } else {
      // ---- phase 0: (i0-3, j0-1); issue 4 of tile t+1's 6 loads
      STG_A01(nxto, ko);
      STG_B01(nxto, ko);
      asm volatile("s_waitcnt vmcnt(4)" ::: "memory");  // tile tt's 6 loads done
      __builtin_amdgcn_s_barrier();
      __builtin_amdgcn_sched_barrier(0);
#pragma unroll
      for (int i = 0; i < 4; i++) { aR[i][0] = ARD(curo, i, 0); aR[i][1] = ARD(curo, i, 1); }
#pragma unroll
      for (int j = 0; j < 2; j++) { bR[j][0] = BRD(curo, j, 0); bR[j][1] = BRD(curo, j, 1); }
      LGKM0;
      MFMA16(0, 0);
      __builtin_amdgcn_s_barrier();
      // ---- phase 1: (i0-3, j2-3); issue remaining 2 loads
      STG_B23(nxto, ko);
#pragma unroll
      for (int j = 0; j < 2; j++) { bR[j][0] = BRD(curo, 2 + j, 0); bR[j][1] = BRD(curo, 2 + j, 1); }
      __builtin_amdgcn_s_barrier();
      LGKM0;
      MFMA16(0, 2);
      __builtin_amdgcn_s_barrier();
    }
    curo = nxto;
  }
  // ---- tail tile: drain all loads once
  asm volatile("s_waitcnt vmcnt(0)" ::: "memory");
  __builtin_amdgcn_s_barrier();
  __builtin_amdgcn_sched_barrier(0);
  if constexpr (AI == 8) {
#pragma unroll
    for (int i = 0; i < 4; i++) { aR[i][0] = ARD(curo, i, 0); aR[i][1] = ARD(curo, i, 1); }
#pragma unroll
    for (int j = 0; j < 2; j++) { bR[j][0] = BRD(curo, j, 0); bR[j][1] = BRD(curo, j, 1); }
    LGKM0;
    MFMA16(0, 0);
#pragma unroll
    for (int j = 0; j < 2; j++) { bR[j][0] = BRD(curo, 2 + j, 0); bR[j][1] = BRD(curo, 2 + j, 1); }
    LGKM0;
    MFMA16(0, 2);
#pragma unroll
    for (int i = 0; i < 4; i++) { aR[i][0] = ARD(curo, 4 + i, 0); aR[i][1] = ARD(curo, 4 + i, 1); }
    LGKM0;
    MFMA16(4, 2);
#pragma unroll
    for (int j = 0; j < 2; j++) { bR[j][0] = BRD(curo, j, 0); bR[j][1] = BRD(curo, j, 1); }
    LGKM0;
    MFMA16(4, 0);
  } else {
#pragma unroll
    for (int i = 0; i < 4; i++) { aR[i][0] = ARD(curo, i, 0); aR[i][1] = ARD(curo, i, 1); }
#pragma unroll
    for (int j = 0; j < 2; j++) { bR[j][0] = BRD(curo, j, 0); bR[j][1] = BRD(curo, j, 1); }
    LGKM0;
    MFMA16(0, 0);
#pragma unroll
    for (int j = 0; j < 2; j++) { bR[j][0] = BRD(curo, 2 + j, 0); bR[j][1] = BRD(curo, 2 + j, 1); }
    LGKM0;
    MFMA16(0, 2);
  }

  // ---- epilogue: D frag col = fr (+j*16), row = kg*4 + reg (+i*16)
  const int row0 = bm * BM + wm * (AI * 16) + (kg << 2);
  if (MODE == 0) {
    const int zz = bn >> 2;
    const float* bias = (zz == 0) ? e0 : ((zz == 1) ? e1 : e2);
    uint16_t* C = (uint16_t*)(Cbase + (long)zz * sCz);
    const int cb = (bn & 3) * 256 + wn * 64 + fr;
#pragma unroll
    for (int i = 0; i < AI; i++) {
#pragma unroll
      for (int j = 0; j < 4; j++) {
        const float bv_ = bias[cb + j * 16];
#pragma unroll
        for (int r = 0; r < 4; r++) {
          C[(long)(row0 + i * 16 + r) * 1024 + cb + j * 16] = f2bf(acc[i][j][r] + bv_);
        }
      }
    }
  } else if (MODE == 1) {
    const int col0 = bn * 256 + wn * 64 + fr;
    uint16_t* C = (uint16_t*)(Cbase + (long)bz * sCz);
    const float* mk = (const float*)((const char*)maskb + (long)bz * sMz);
#pragma unroll
    for (int i = 0; i < AI; i++) {
#pragma unroll
      for (int j = 0; j < 4; j++) {
#pragma unroll
        for (int r = 0; r < 4; r++) {
          const long idx = (long)(row0 + i * 16 + r) * N + col0 + j * 16;
          C[idx] = f2bf(__expf(acc[i][j][r] * scale + mk[idx]));
        }
      }
    }
  } else {
    const int col0 = bn * 256 + wn * 64 + fr;
    float* C = (float*)(Cbase + (long)bz * sCz);
    const float* ri = rowinv + (long)bz * 2048;
#pragma unroll
    for (int i = 0; i < AI; i++) {
#pragma unroll
      for (int j = 0; j < 4; j++) {
#pragma unroll
        for (int r = 0; r < 4; r++) {
          const int row = row0 + i * 16 + r;
          C[(long)row * N + col0 + j * 16] = acc[i][j][r] * ri[row];
        }
      }
    }
  }
#undef ARD
#undef BRD
#undef STG_A01
#undef STG_A23
#undef STG_B01
#undef STG_B23
#undef LGKM0
#undef MFMA16
}

// ---------------- launch ----------------
extern "C" void kernel_launch(void* const* d_in, const int* in_sizes, int n_in,
                              void* d_out, int out_size, void* d_ws, size_t ws_size,
                              hipStream_t stream) {
  const float* hs = (const float*)d_in[0];
  const float* mask = (const float*)d_in[1];
  const float* Wq = (const float*)d_in[2];
  const float* bq = (const float*)d_in[3];
  const float* Wk = (const float*)d_in[4];
  const float* bk = (const float*)d_in[5];
  const float* Wv = (const float*)d_in[6];
  const float* bv = (const float*)d_in[7];
  float* out = (float*)d_out;

  char* ws = (char*)d_ws;
  uint16_t* hsb = (uint16_t*)ws;                  // [8192][1024] bf16    16MB
  uint16_t* WT = (uint16_t*)(ws + (16L << 20));   // [3][1024][1024]       6MB
  uint16_t* QKV = (uint16_t*)(ws + (22L << 20));  // [3][8192][1024]      48MB
  uint16_t* Vt = (uint16_t*)(ws + (70L << 20));   // [4][1024(d)][2048]   16MB
  uint16_t* E = (uint16_t*)(ws + (86L << 20));    // [4][2048][2048] bf16 32MB
  float* invl = (float*)(ws + (118L << 20));      // [8192] f32           32KB

  // 1) hs -> bf16
  cvt_f32_to_bf16<<<4096, 256, 0, stream>>>(hs, hsb);
  // 2) W -> W^T bf16 (x3; contiguous => WT is [3072][1024])
  cvt_w_transpose<<<dim3(16, 8, 3), 64, 0, stream>>>(Wq, Wk, Wv, WT);
  // 3) fused QKV projection: [8192x1024] x [3072x1024]^T, 128x256 tiles,
  //    768 blocks = 3 full CU-waves; output slab + bias selected by bn>>2
  gemmX<0, 4><<<dim3(64, 12, 1), 512, 0, stream>>>(
      hsb, 0L, WT, 0L, 1024, 3072, (char*)QKV, 16L << 20,
      bq, bk, bv, nullptr, 0L, 0.f, nullptr);
  // 4) V transpose per batch
  transpose_v<<<dim3(32, 16, 4), 256, 0, stream>>>(QKV + 2L * 8192 * 1024, Vt);
  // 5) E = bf16(exp(Q K^T / 32 + mask))   (256x256 4-phase, exp fused)
  gemmX<1, 8><<<dim3(8, 8, 4), 512, 0, stream>>>(
      QKV, 4L << 20, QKV + 8192L * 1024, 4L << 20, 1024, 2048, (char*)E, 8L << 20,
      nullptr, nullptr, nullptr, mask, 16L << 20, 0.03125f, nullptr);
  // 6) inv row sums of E
  rowsum_inv<<<8192, 256, 0, stream>>>(E, invl);
  // 7) out = (E Vt^T) * invl  (128x256 2-phase, K=2048, f32 out)
  gemmX<2, 4><<<dim3(16, 4, 4), 512, 0, stream>>>(
      E, 8L << 20, Vt, 4L << 20, 2048, 1024, (char*)out, 8L << 20,
      nullptr, nullptr, nullptr, nullptr, 0L, 0.f, invl);
}